// Round 2
// baseline (935.137 us; speedup 1.0000x reference)
//
#include <hip/hip_runtime.h>
#include <math.h>

#define NB 16
#define NT 24
#define HP 56
#define WP 56
#define NF 32
#define ND (HP*WP*NF)   // 100352
#define NHPQ 14
#define HPITCH 40       // padded f-pitch of h_lds rows (ushorts) -> 80B, bank-spread
#define LN_EPS 1e-3f

typedef __attribute__((ext_vector_type(8))) short short8;
typedef __attribute__((ext_vector_type(4))) float floatx4;

__device__ __forceinline__ float tanh_fast(float x){
    float e = __expf(2.0f*x);
    return 1.0f - 2.0f*__builtin_amdgcn_rcpf(e + 1.0f);
}
__device__ __forceinline__ float hsig(float z){
    return fminf(fmaxf(z*0.2f + 0.5f, 0.0f), 1.0f);
}
__device__ __forceinline__ ushort f2bf(float v){  // fp32 -> bf16 bits, RNE
    unsigned u = __float_as_uint(v);
    return (ushort)((u + 0x7fffu + ((u >> 16) & 1u)) >> 16);
}

// Persistent fused ConvLSTM+LN, v2.
// grid (14,16) = 224 blocks, 512 threads = 8 waves. LDS ~120KB -> 1 block/CU,
// guaranteed co-resident. Wave w: hp-row = w>>1, f-half = w&1.
// Per wave: M=64 (wp), N=64 (4 gates x 16 f)  -> acc[4][4], c/h in regs.
// Changes vs v1: 8 waves/CU (was 4); h_lds row pitch padded 32->40 ushorts
// (kills 8-way epilogue write bank conflict); halo loads issued to regs and
// committed after input-conv MFMAs (T14); per-batch stats wait moved to AFTER
// the MFMA phase (one full step of slack -> off the critical path).
__global__ __launch_bounds__(512, 2)
void convlstm_persist(const float* __restrict__ x,      // (B,T,112,112,3)
                      const float* __restrict__ Wk,     // (3,3,3,128)
                      const float* __restrict__ Uk,     // (3,3,32,128)
                      const float* __restrict__ bias,   // (128)
                      const float* __restrict__ gamma,  // (D)
                      const float* __restrict__ beta,   // (D)
                      ushort* __restrict__ hbuf0,       // (B,56,56,32) bf16 halo
                      ushort* __restrict__ hbuf1,
                      float* __restrict__ out,          // (B,T,D)
                      float* __restrict__ stats,        // (B*T,2)
                      int* __restrict__ cnt,            // (B*T)
                      int* __restrict__ flags)          // (T,B,14)
{
    __shared__ __attribute__((aligned(16))) ushort h_lds[6*66*HPITCH]; // 31680 B
    __shared__ __attribute__((aligned(16))) ushort x_lds[9*344];       //  6192 B
    __shared__ __attribute__((aligned(16))) ushort u_lds[9*128*32];    // 73728 B
    __shared__ __attribute__((aligned(16))) ushort wk_lds[128*32];     //  8192 B
    __shared__ float bcast[2];
    __shared__ float sred[8][2];

    const int tid  = threadIdx.x;
    const int hpq  = blockIdx.x;
    const int b    = blockIdx.y;
    const int lane = tid & 63;
    const int w    = tid >> 6;        // wave id
    const int row  = w >> 1;          // local hp row 0..3
    const int fh   = w & 1;           // f-half 0..1
    const int col  = lane & 15;
    const int q    = lane >> 4;
    const int q8   = q * 8;
    const int hp_g = hpq*4 + row;

    // ---- one-time init: zero LDS pads, convert weights to bf16 LDS ----
    for (int e = tid; e < 6*66*HPITCH; e += 512) h_lds[e] = 0;
    for (int e = tid; e < 9*344;       e += 512) x_lds[e] = 0;
    for (int e = tid; e < 9*32*128; e += 512){
        int tap = e >> 12, k = (e >> 7) & 31, n = e & 127;
        u_lds[(tap*128 + n)*32 + k] = f2bf(Uk[e]);
    }
    for (int e = tid; e < 128*32; e += 512){
        int n = e >> 5, k = e & 31;
        wk_lds[e] = (k < 27) ? f2bf(Wk[k*128 + n]) : (ushort)0;
    }

    // ---- persistent registers ----
    float bg[4];
    #pragma unroll
    for (int g = 0; g < 4; g++) bg[g] = bias[g*32 + fh*16 + col];

    float gr[4][4], br[4][4], creg[4][4], hreg[4][4];
    #pragma unroll
    for (int mt = 0; mt < 4; mt++)
      #pragma unroll
      for (int reg = 0; reg < 4; reg++){
          int wp = mt*16 + q*4 + reg;
          creg[mt][reg] = 0.f;
          hreg[mt][reg] = 0.f;
          if (wp < WP){
              size_t idx = (size_t)(hp_g*WP + wp)*NF + fh*16 + col;
              gr[mt][reg] = gamma[idx];
              br[mt][reg] = beta[idx];
          } else { gr[mt][reg] = 0.f; br[mt][reg] = 0.f; }
      }

    __syncthreads();   // init complete

    for (int t = 0; t < NT; ++t){
        // ---- stage x rows 8hpq..8hpq+8 (vectorized fp32->bf16) ----
        {
            const float* xt = x + ((size_t)(b*NT + t))*(112*112*3);
            for (int e = tid; e < 9*84; e += 512){
                int rrow = e / 84;
                int c4   = e - rrow*84;
                int rg   = 8*hpq + rrow;
                if (rg < 112){
                    float4 v = *(const float4*)&xt[rg*336 + c4*4];
                    ushort4 s4 = {f2bf(v.x), f2bf(v.y), f2bf(v.z), f2bf(v.w)};
                    *(ushort4*)&x_lds[rrow*344 + c4*4] = s4;
                }
            }
        }
        // ---- wait ONLY neighbor halos(t-1); stats wait deferred to post-MFMA ----
        if (t > 0 && tid == 0){
            const int fb = ((t-1)*NB + b)*NHPQ;
            if (hpq > 0)
                while (__hip_atomic_load(&flags[fb + hpq-1], __ATOMIC_ACQUIRE, __HIP_MEMORY_SCOPE_AGENT) == 0)
                    __builtin_amdgcn_s_sleep(2);
            if (hpq < NHPQ-1)
                while (__hip_atomic_load(&flags[fb + hpq+1], __ATOMIC_ACQUIRE, __HIP_MEMORY_SCOPE_AGENT) == 0)
                    __builtin_amdgcn_s_sleep(2);
        }
        __syncthreads();                           // B1: x_lds ready, halos released

        // ---- issue halo loads to REGISTERS (latency hidden under input conv) ----
        uint4 hv = make_uint4(0u,0u,0u,0u);
        int hoff = -1;
        if (t > 0 && tid < 448){
            const ushort* hsrc = ((t & 1) ? hbuf0 : hbuf1) + (size_t)b*ND;
            int rsel = (tid >= 224);
            int rem  = tid - rsel*224;
            int cg   = rem >> 2, cq = rem & 3;
            int rg   = rsel ? (hpq*4 + 4) : (hpq*4 - 1);
            int ldr  = rsel ? 5 : 0;
            if (rg >= 0 && rg < HP){
                hv   = *(const uint4*)&hsrc[((size_t)rg*WP + cg)*NF + cq*8];
                hoff = (ldr*66 + 1 + cg)*HPITCH + cq*8;
            }
        }

        // ---- accumulators with bias folded ----
        floatx4 acc[4][4];
        #pragma unroll
        for (int g = 0; g < 4; g++){
            floatx4 bv = (floatx4){bg[g], bg[g], bg[g], bg[g]};
            #pragma unroll
            for (int mt = 0; mt < 4; mt++) acc[mt][g] = bv;
        }

        // ---- input conv: one K=32 MFMA step (k>=27 zero) ----
        {
            short8 ax[4];
            #pragma unroll
            for (int mt = 0; mt < 4; mt++){
                int wp = mt*16 + col;
                short8 v;
                #pragma unroll
                for (int j = 0; j < 8; j++){
                    int k = q8 + j;
                    ushort bits = 0;
                    if (k < 27){
                        int dy = k/9; int rr = k - dy*9; int dx = rr/3; int cc = rr - dx*3;
                        int xc = 2*wp + dx; if (xc > 112) xc = 112;
                        bits = x_lds[(2*row + dy)*344 + xc*3 + cc];
                    }
                    v[j] = (short)bits;
                }
                ax[mt] = v;
            }
            #pragma unroll
            for (int g = 0; g < 4; g++){
                short8 bx = *(const short8*)&wk_lds[(g*32 + fh*16 + col)*32 + q8];
                #pragma unroll
                for (int mt = 0; mt < 4; mt++)
                    acc[mt][g] = __builtin_amdgcn_mfma_f32_16x16x32_bf16(ax[mt], bx, acc[mt][g], 0, 0, 0);
            }
        }

        // ---- commit halo regs -> LDS ----
        if (hoff >= 0) *(uint4*)&h_lds[hoff] = hv;
        __syncthreads();                           // B2: h_lds (interior t-1 + halos) complete

        // ---- 9 recurrent taps, K=32 each ----
        if (t > 0){
            #pragma unroll
            for (int tap = 0; tap < 9; tap++){
                int dy = tap/3, dx = tap - dy*3;
                short8 a_[4], bb_[4];
                #pragma unroll
                for (int g = 0; g < 4; g++)
                    bb_[g] = *(const short8*)&u_lds[(tap*128 + g*32 + fh*16 + col)*32 + q8];
                #pragma unroll
                for (int mt = 0; mt < 4; mt++)
                    a_[mt] = *(const short8*)&h_lds[((row + dy)*66 + mt*16 + col + dx)*HPITCH + q8];
                #pragma unroll
                for (int mt = 0; mt < 4; mt++)
                    #pragma unroll
                    for (int g = 0; g < 4; g++)
                        acc[mt][g] = __builtin_amdgcn_mfma_f32_16x16x32_bf16(a_[mt], bb_[g], acc[mt][g], 0, 0, 0);
            }
        }
        __syncthreads();                           // B3: all waves done reading h_lds/x_lds

        // ---- deferred normalized write of out[t-1] (stats have a full step of slack) ----
        if (t > 0){
            if (tid == 0){
                while (__hip_atomic_load(&cnt[b*NT + t-1], __ATOMIC_ACQUIRE, __HIP_MEMORY_SCOPE_AGENT) < NHPQ)
                    __builtin_amdgcn_s_sleep(2);
                float s  = __hip_atomic_load(&stats[(size_t)(b*NT + t-1)*2],     __ATOMIC_RELAXED, __HIP_MEMORY_SCOPE_AGENT);
                float ss = __hip_atomic_load(&stats[(size_t)(b*NT + t-1)*2 + 1], __ATOMIC_RELAXED, __HIP_MEMORY_SCOPE_AGENT);
                float m  = s * (1.0f/(float)ND);
                float v  = ss * (1.0f/(float)ND) - m*m;
                bcast[0] = m;
                bcast[1] = rsqrtf(v + LN_EPS);
            }
            __syncthreads();                       // B3b
            const float mu = bcast[0], rs = bcast[1];
            float* orow = out + ((size_t)(b*NT + t - 1))*ND;
            #pragma unroll
            for (int mt = 0; mt < 4; mt++)
              #pragma unroll
              for (int reg = 0; reg < 4; reg++){
                  int wp = mt*16 + q*4 + reg;
                  if (wp < WP)
                      orow[(size_t)(hp_g*WP + wp)*NF + fh*16 + col] =
                          (hreg[mt][reg] - mu)*rs*gr[mt][reg] + br[mt][reg];
              }
        }

        // ---- LSTM pointwise epilogue: c,h in regs, h->LDS interior ----
        float lsum = 0.f, lss = 0.f;
        #pragma unroll
        for (int mt = 0; mt < 4; mt++)
          #pragma unroll
          for (int reg = 0; reg < 4; reg++){
              int wp = mt*16 + q*4 + reg;
              float zi = acc[mt][0][reg];
              float zf = acc[mt][1][reg];
              float zc = acc[mt][2][reg];
              float zo = acc[mt][3][reg];
              float ig = hsig(zi), fg = hsig(zf), og = hsig(zo);
              float cn = fg*creg[mt][reg] + ig*tanh_fast(zc);
              float hv2 = og*tanh_fast(cn);
              if (wp < WP){
                  creg[mt][reg] = cn;
                  hreg[mt][reg] = hv2;
                  h_lds[((row + 1)*66 + 1 + wp)*HPITCH + fh*16 + col] = f2bf(hv2);
                  lsum += hv2;
                  lss  += hv2*hv2;
              }
          }

        // ---- halo rows to global (own-row, own f-half; no extra barrier) ----
        if (row == 0 || row == 3){
            ushort* hdst = ((t & 1) ? hbuf1 : hbuf0) + (size_t)b*ND;
            int rg  = hpq*4 + row;
            int ldr = row ? 4 : 1;
            for (int e = lane; e < 112; e += 64){
                int cg = e >> 1, hf = e & 1;
                *(uint4*)&hdst[((size_t)rg*WP + cg)*NF + fh*16 + hf*8] =
                    *(const uint4*)&h_lds[(ldr*66 + 1 + cg)*HPITCH + fh*16 + hf*8];
            }
        }

        // ---- stats: wave reduce -> LDS partials -> single atomic per block ----
        #pragma unroll
        for (int off = 32; off > 0; off >>= 1){
            lsum += __shfl_down(lsum, off);
            lss  += __shfl_down(lss, off);
        }
        if (lane == 0){ sred[w][0] = lsum; sred[w][1] = lss; }

        __syncthreads();   // B4: drains LDS writes + all waves' global stores
        if (tid == 0){
            float a0 = 0.f, a1 = 0.f;
            #pragma unroll
            for (int i = 0; i < 8; i++){ a0 += sred[i][0]; a1 += sred[i][1]; }
            atomicAdd(&stats[(size_t)(b*NT + t)*2],     a0);
            atomicAdd(&stats[(size_t)(b*NT + t)*2 + 1], a1);
            __hip_atomic_fetch_add(&cnt[b*NT + t], 1, __ATOMIC_RELEASE, __HIP_MEMORY_SCOPE_AGENT);
            __hip_atomic_fetch_add(&flags[((size_t)t*NB + b)*NHPQ + hpq], 1, __ATOMIC_RELEASE, __HIP_MEMORY_SCOPE_AGENT);
        }
    }

    // ---- final: normalized write of out[NT-1] ----
    if (tid == 0){
        while (__hip_atomic_load(&cnt[b*NT + NT-1], __ATOMIC_ACQUIRE, __HIP_MEMORY_SCOPE_AGENT) < NHPQ)
            __builtin_amdgcn_s_sleep(2);
        float s  = __hip_atomic_load(&stats[(size_t)(b*NT + NT-1)*2],     __ATOMIC_RELAXED, __HIP_MEMORY_SCOPE_AGENT);
        float ss = __hip_atomic_load(&stats[(size_t)(b*NT + NT-1)*2 + 1], __ATOMIC_RELAXED, __HIP_MEMORY_SCOPE_AGENT);
        float m  = s * (1.0f/(float)ND);
        float v  = ss * (1.0f/(float)ND) - m*m;
        bcast[0] = m;
        bcast[1] = rsqrtf(v + LN_EPS);
    }
    __syncthreads();
    {
        const float mu = bcast[0], rs = bcast[1];
        float* orow = out + ((size_t)(b*NT + NT - 1))*ND;
        #pragma unroll
        for (int mt = 0; mt < 4; mt++)
          #pragma unroll
          for (int reg = 0; reg < 4; reg++){
              int wp = mt*16 + q*4 + reg;
              if (wp < WP)
                  orow[(size_t)(hp_g*WP + wp)*NF + fh*16 + col] =
                      (hreg[mt][reg] - mu)*rs*gr[mt][reg] + br[mt][reg];
          }
    }
}

extern "C" void kernel_launch(void* const* d_in, const int* in_sizes, int n_in,
                              void* d_out, int out_size, void* d_ws, size_t ws_size,
                              hipStream_t stream)
{
    const float* x     = (const float*)d_in[0];
    const float* Wk    = (const float*)d_in[1];
    const float* Uk    = (const float*)d_in[2];
    const float* bias  = (const float*)d_in[3];
    const float* gamma = (const float*)d_in[4];
    const float* beta  = (const float*)d_in[5];
    float* out = (float*)d_out;

    // ws layout:
    //   hbuf0  bf16  NB*ND          (3.21 MB)
    //   hbuf1  bf16  NB*ND          (3.21 MB)
    //   stats  fp32  NB*NT*2        \
    //   cnt    int   NB*NT           } one contiguous memset
    //   flags  int   NT*NB*NHPQ    /
    char* p = (char*)d_ws;
    ushort* hbuf0 = (ushort*)p; p += (size_t)NB*ND*2;
    ushort* hbuf1 = (ushort*)p; p += (size_t)NB*ND*2;
    float*  stats = (float*)p;  p += (size_t)NB*NT*2*4;
    int*    cnt   = (int*)p;    p += (size_t)NB*NT*4;
    int*    flags = (int*)p;

    hipMemsetAsync(stats, 0, (size_t)(NB*NT*2*4 + NB*NT*4 + NT*NB*NHPQ*4), stream);
    hipLaunchKernelGGL(convlstm_persist, dim3(NHPQ, NB), dim3(512), 0, stream,
                       x, Wk, Uk, bias, gamma, beta,
                       hbuf0, hbuf1, out, stats, cnt, flags);
}

// Round 3
// 571.323 us; speedup vs baseline: 1.6368x; 1.6368x over previous
//
#include <hip/hip_runtime.h>
#include <math.h>

#define NB 16
#define NT 24
#define HP 56
#define WP 56
#define NF 32
#define ND (HP*WP*NF)   // 100352
#define NHPQ 14
#define HPITCH 36       // h_lds f-pitch (ushorts): epilogue u16 writes 2-way, b128 reads <=4-way
#define LN_EPS 1e-3f

typedef __attribute__((ext_vector_type(8))) short short8;
typedef __attribute__((ext_vector_type(4))) float floatx4;

// relaxed agent-scope atomics: routed to the coherent point (sc1) WITHOUT
// buffer_inv / buffer_wbl2 cache maintenance (the round-2 killer).
#define AT_LD(p)     __hip_atomic_load((p), __ATOMIC_RELAXED, __HIP_MEMORY_SCOPE_AGENT)
#define AT_ST(p, v)  __hip_atomic_store((p), (v), __ATOMIC_RELAXED, __HIP_MEMORY_SCOPE_AGENT)
#define AT_ADD(p, v) __hip_atomic_fetch_add((p), (v), __ATOMIC_RELAXED, __HIP_MEMORY_SCOPE_AGENT)

__device__ __forceinline__ float tanh_fast(float x){
    float e = __expf(2.0f*x);
    return 1.0f - 2.0f*__builtin_amdgcn_rcpf(e + 1.0f);
}
__device__ __forceinline__ float hsig(float z){
    return fminf(fmaxf(z*0.2f + 0.5f, 0.0f), 1.0f);
}
__device__ __forceinline__ ushort f2bf(float v){  // fp32 -> bf16 bits, RNE
    unsigned u = __float_as_uint(v);
    return (ushort)((u + 0x7fffu + ((u >> 16) & 1u)) >> 16);
}

// Persistent fused ConvLSTM+LN, v3.
// grid (14,16) = 224 blocks, 512 threads = 8 waves, 1 block/CU (LDS ~117KB)
// -> all blocks co-resident, spin-waits safe.
// v3 change: sync protocol rebuilt with RELAXED agent atomics only.
//   - flags/cnt/stats: relaxed fetch_add / relaxed polls (no L2 inv per poll)
//   - halo h data: relaxed agent 4B atomic ld/st (coherent-point routed,
//     immune to stale L1/L2, compiler-tracked -> safe waitcnts)
//   - ordering: explicit s_waitcnt vmcnt(0) before flag posts
__global__ __launch_bounds__(512, 2)
void convlstm_persist(const float* __restrict__ x,      // (B,T,112,112,3)
                      const float* __restrict__ Wk,     // (3,3,3,128)
                      const float* __restrict__ Uk,     // (3,3,32,128)
                      const float* __restrict__ bias,   // (128)
                      const float* __restrict__ gamma,  // (D)
                      const float* __restrict__ beta,   // (D)
                      ushort* __restrict__ hbuf0,       // (B,56,56,32) bf16 halo
                      ushort* __restrict__ hbuf1,
                      float* __restrict__ out,          // (B,T,D)
                      float* __restrict__ stats,        // (B*T,2)
                      int* __restrict__ cnt,            // (B*T)
                      int* __restrict__ flags)          // (T,B,14)
{
    __shared__ __attribute__((aligned(16))) ushort h_lds[6*66*HPITCH]; // 28512 B
    __shared__ __attribute__((aligned(16))) ushort x_lds[9*344];       //  6192 B
    __shared__ __attribute__((aligned(16))) ushort u_lds[9*128*32];    // 73728 B
    __shared__ __attribute__((aligned(16))) ushort wk_lds[128*32];     //  8192 B
    __shared__ float bcast[2];
    __shared__ float sred[8][2];

    const int tid  = threadIdx.x;
    const int hpq  = blockIdx.x;
    const int b    = blockIdx.y;
    const int lane = tid & 63;
    const int w    = tid >> 6;        // wave id
    const int row  = w >> 1;          // local hp row 0..3
    const int fh   = w & 1;           // f-half 0..1
    const int col  = lane & 15;
    const int q    = lane >> 4;
    const int q8   = q * 8;
    const int hp_g = hpq*4 + row;

    // ---- one-time init: zero LDS pads, convert weights to bf16 LDS ----
    for (int e = tid; e < 6*66*HPITCH; e += 512) h_lds[e] = 0;
    for (int e = tid; e < 9*344;       e += 512) x_lds[e] = 0;
    for (int e = tid; e < 9*32*128; e += 512){
        int tap = e >> 12, k = (e >> 7) & 31, n = e & 127;
        u_lds[(tap*128 + n)*32 + k] = f2bf(Uk[e]);
    }
    for (int e = tid; e < 128*32; e += 512){
        int n = e >> 5, k = e & 31;
        wk_lds[e] = (k < 27) ? f2bf(Wk[k*128 + n]) : (ushort)0;
    }

    // ---- persistent registers ----
    float bg[4];
    #pragma unroll
    for (int g = 0; g < 4; g++) bg[g] = bias[g*32 + fh*16 + col];

    float gr[4][4], br[4][4], creg[4][4], hreg[4][4];
    #pragma unroll
    for (int mt = 0; mt < 4; mt++)
      #pragma unroll
      for (int reg = 0; reg < 4; reg++){
          int wp = mt*16 + q*4 + reg;
          creg[mt][reg] = 0.f;
          hreg[mt][reg] = 0.f;
          if (wp < WP){
              size_t idx = (size_t)(hp_g*WP + wp)*NF + fh*16 + col;
              gr[mt][reg] = gamma[idx];
              br[mt][reg] = beta[idx];
          } else { gr[mt][reg] = 0.f; br[mt][reg] = 0.f; }
      }

    __syncthreads();   // init complete

    for (int t = 0; t < NT; ++t){
        // ---- stage x rows 8hpq..8hpq+8 (vectorized fp32->bf16) ----
        {
            const float* xt = x + ((size_t)(b*NT + t))*(112*112*3);
            for (int e = tid; e < 9*84; e += 512){
                int rrow = e / 84;
                int c4   = e - rrow*84;
                int rg   = 8*hpq + rrow;
                if (rg < 112){
                    float4 v = *(const float4*)&xt[rg*336 + c4*4];
                    ushort4 s4 = {f2bf(v.x), f2bf(v.y), f2bf(v.z), f2bf(v.w)};
                    *(ushort4*)&x_lds[rrow*344 + c4*4] = s4;
                }
            }
        }
        // ---- wait ONLY neighbor halos(t-1): relaxed polls, no cache ops ----
        if (t > 0 && tid == 0){
            const int fb = ((t-1)*NB + b)*NHPQ;
            if (hpq > 0)
                while (AT_LD(&flags[fb + hpq-1]) == 0) __builtin_amdgcn_s_sleep(4);
            if (hpq < NHPQ-1)
                while (AT_LD(&flags[fb + hpq+1]) == 0) __builtin_amdgcn_s_sleep(4);
            asm volatile("" ::: "memory");
        }
        __syncthreads();                           // B1: x_lds ready, halos released

        // ---- issue halo loads (coherent 4B, compiler-tracked); commit after conv ----
        uint4 hv = {0u,0u,0u,0u};
        int hoff = -1;
        if (t > 0 && tid < 448){
            const ushort* hsrc = ((t & 1) ? hbuf0 : hbuf1) + (size_t)b*ND;
            int rsel = (tid >= 224);
            int rem  = tid - rsel*224;
            int cg   = rem >> 2, cq = rem & 3;
            int rg   = rsel ? (hpq*4 + 4) : (hpq*4 - 1);
            int ldr  = rsel ? 5 : 0;
            if (rg >= 0 && rg < HP){
                const uint* sp = (const uint*)&hsrc[((size_t)rg*WP + cg)*NF + cq*8];
                hv.x = AT_LD(sp + 0);
                hv.y = AT_LD(sp + 1);
                hv.z = AT_LD(sp + 2);
                hv.w = AT_LD(sp + 3);
                hoff = (ldr*66 + 1 + cg)*HPITCH + cq*8;
            }
        }

        // ---- accumulators with bias folded ----
        floatx4 acc[4][4];
        #pragma unroll
        for (int g = 0; g < 4; g++){
            floatx4 bv = (floatx4){bg[g], bg[g], bg[g], bg[g]};
            #pragma unroll
            for (int mt = 0; mt < 4; mt++) acc[mt][g] = bv;
        }

        // ---- input conv: one K=32 MFMA step (k>=27 zero) ----
        {
            short8 ax[4];
            #pragma unroll
            for (int mt = 0; mt < 4; mt++){
                int wp = mt*16 + col;
                short8 v;
                #pragma unroll
                for (int j = 0; j < 8; j++){
                    int k = q8 + j;
                    ushort bits = 0;
                    if (k < 27){
                        int dy = k/9; int rr = k - dy*9; int dx = rr/3; int cc = rr - dx*3;
                        int xc = 2*wp + dx; if (xc > 112) xc = 112;
                        bits = x_lds[(2*row + dy)*344 + xc*3 + cc];
                    }
                    v[j] = (short)bits;
                }
                ax[mt] = v;
            }
            #pragma unroll
            for (int g = 0; g < 4; g++){
                short8 bx = *(const short8*)&wk_lds[(g*32 + fh*16 + col)*32 + q8];
                #pragma unroll
                for (int mt = 0; mt < 4; mt++)
                    acc[mt][g] = __builtin_amdgcn_mfma_f32_16x16x32_bf16(ax[mt], bx, acc[mt][g], 0, 0, 0);
            }
        }

        // ---- commit halo regs -> LDS (compiler inserts the vmcnt wait) ----
        if (hoff >= 0) *(uint4*)&h_lds[hoff] = hv;
        __syncthreads();                           // B2: h_lds (interior t-1 + halos) complete

        // ---- 9 recurrent taps, K=32 each ----
        if (t > 0){
            #pragma unroll
            for (int tap = 0; tap < 9; tap++){
                int dy = tap/3, dx = tap - dy*3;
                short8 a_[4], bb_[4];
                #pragma unroll
                for (int g = 0; g < 4; g++)
                    bb_[g] = *(const short8*)&u_lds[(tap*128 + g*32 + fh*16 + col)*32 + q8];
                #pragma unroll
                for (int mt = 0; mt < 4; mt++)
                    a_[mt] = *(const short8*)&h_lds[((row + dy)*66 + mt*16 + col + dx)*HPITCH + q8];
                #pragma unroll
                for (int mt = 0; mt < 4; mt++)
                    #pragma unroll
                    for (int g = 0; g < 4; g++)
                        acc[mt][g] = __builtin_amdgcn_mfma_f32_16x16x32_bf16(a_[mt], bb_[g], acc[mt][g], 0, 0, 0);
            }
        }
        __syncthreads();                           // B3: all waves done reading h_lds/x_lds

        // ---- deferred normalized write of out[t-1] (one step of slack) ----
        if (t > 0){
            if (tid == 0){
                while (AT_LD(&cnt[b*NT + t-1]) < NHPQ) __builtin_amdgcn_s_sleep(4);
                asm volatile("" ::: "memory");
                float s  = AT_LD(&stats[(size_t)(b*NT + t-1)*2]);
                float ss = AT_LD(&stats[(size_t)(b*NT + t-1)*2 + 1]);
                float m  = s * (1.0f/(float)ND);
                float v  = ss * (1.0f/(float)ND) - m*m;
                bcast[0] = m;
                bcast[1] = rsqrtf(v + LN_EPS);
            }
            __syncthreads();                       // B3b
            const float mu = bcast[0], rs = bcast[1];
            float* orow = out + ((size_t)(b*NT + t - 1))*ND;
            #pragma unroll
            for (int mt = 0; mt < 4; mt++)
              #pragma unroll
              for (int reg = 0; reg < 4; reg++){
                  int wp = mt*16 + q*4 + reg;
                  if (wp < WP)
                      orow[(size_t)(hp_g*WP + wp)*NF + fh*16 + col] =
                          (hreg[mt][reg] - mu)*rs*gr[mt][reg] + br[mt][reg];
              }
        }

        // ---- LSTM pointwise epilogue: c,h in regs, h->LDS interior ----
        float lsum = 0.f, lss = 0.f;
        #pragma unroll
        for (int mt = 0; mt < 4; mt++)
          #pragma unroll
          for (int reg = 0; reg < 4; reg++){
              int wp = mt*16 + q*4 + reg;
              float zi = acc[mt][0][reg];
              float zf = acc[mt][1][reg];
              float zc = acc[mt][2][reg];
              float zo = acc[mt][3][reg];
              float ig = hsig(zi), fg = hsig(zf), og = hsig(zo);
              float cn = fg*creg[mt][reg] + ig*tanh_fast(zc);
              float hv2 = og*tanh_fast(cn);
              if (wp < WP){
                  creg[mt][reg] = cn;
                  hreg[mt][reg] = hv2;
                  h_lds[((row + 1)*66 + 1 + wp)*HPITCH + fh*16 + col] = f2bf(hv2);
                  lsum += hv2;
                  lss  += hv2*hv2;
              }
          }

        // ---- halo rows to global: coherent 4B stores (own-row, own f-half) ----
        if (row == 0 || row == 3){
            ushort* hdst = ((t & 1) ? hbuf1 : hbuf0) + (size_t)b*ND;
            int rg  = hpq*4 + row;
            int ldr = row ? 4 : 1;
            for (int e = lane; e < 112; e += 64){
                int cg = e >> 1, hf = e & 1;
                uint4 v = *(const uint4*)&h_lds[(ldr*66 + 1 + cg)*HPITCH + fh*16 + hf*8];
                uint* dp = (uint*)&hdst[((size_t)rg*WP + cg)*NF + fh*16 + hf*8];
                AT_ST(dp + 0, v.x);
                AT_ST(dp + 1, v.y);
                AT_ST(dp + 2, v.z);
                AT_ST(dp + 3, v.w);
            }
        }

        // ---- stats: wave reduce -> LDS partials ----
        #pragma unroll
        for (int off = 32; off > 0; off >>= 1){
            lsum += __shfl_down(lsum, off);
            lss  += __shfl_down(lss, off);
        }
        if (lane == 0){ sred[w][0] = lsum; sred[w][1] = lss; }

        // drain own halo/out stores before the barrier, so tid0's flag post
        // after B4 is ordered behind ALL waves' coherent stores
        asm volatile("s_waitcnt vmcnt(0)" ::: "memory");
        __syncthreads();   // B4
        if (tid == 0){
            float a0 = 0.f, a1 = 0.f;
            #pragma unroll
            for (int i = 0; i < 8; i++){ a0 += sred[i][0]; a1 += sred[i][1]; }
            AT_ADD(&stats[(size_t)(b*NT + t)*2],     a0);
            AT_ADD(&stats[(size_t)(b*NT + t)*2 + 1], a1);
            // stats adds must be globally visible before cnt/flags increments
            asm volatile("s_waitcnt vmcnt(0)" ::: "memory");
            AT_ADD(&cnt[b*NT + t], 1);
            AT_ADD(&flags[((size_t)t*NB + b)*NHPQ + hpq], 1);
        }
    }

    // ---- final: normalized write of out[NT-1] ----
    if (tid == 0){
        while (AT_LD(&cnt[b*NT + NT-1]) < NHPQ) __builtin_amdgcn_s_sleep(4);
        asm volatile("" ::: "memory");
        float s  = AT_LD(&stats[(size_t)(b*NT + NT-1)*2]);
        float ss = AT_LD(&stats[(size_t)(b*NT + NT-1)*2 + 1]);
        float m  = s * (1.0f/(float)ND);
        float v  = ss * (1.0f/(float)ND) - m*m;
        bcast[0] = m;
        bcast[1] = rsqrtf(v + LN_EPS);
    }
    __syncthreads();
    {
        const float mu = bcast[0], rs = bcast[1];
        float* orow = out + ((size_t)(b*NT + NT - 1))*ND;
        #pragma unroll
        for (int mt = 0; mt < 4; mt++)
          #pragma unroll
          for (int reg = 0; reg < 4; reg++){
              int wp = mt*16 + q*4 + reg;
              if (wp < WP)
                  orow[(size_t)(hp_g*WP + wp)*NF + fh*16 + col] =
                      (hreg[mt][reg] - mu)*rs*gr[mt][reg] + br[mt][reg];
          }
    }
}

extern "C" void kernel_launch(void* const* d_in, const int* in_sizes, int n_in,
                              void* d_out, int out_size, void* d_ws, size_t ws_size,
                              hipStream_t stream)
{
    const float* x     = (const float*)d_in[0];
    const float* Wk    = (const float*)d_in[1];
    const float* Uk    = (const float*)d_in[2];
    const float* bias  = (const float*)d_in[3];
    const float* gamma = (const float*)d_in[4];
    const float* beta  = (const float*)d_in[5];
    float* out = (float*)d_out;

    // ws layout:
    //   hbuf0  bf16  NB*ND          (3.21 MB)
    //   hbuf1  bf16  NB*ND          (3.21 MB)
    //   stats  fp32  NB*NT*2        \
    //   cnt    int   NB*NT           } one contiguous memset
    //   flags  int   NT*NB*NHPQ    /
    char* p = (char*)d_ws;
    ushort* hbuf0 = (ushort*)p; p += (size_t)NB*ND*2;
    ushort* hbuf1 = (ushort*)p; p += (size_t)NB*ND*2;
    float*  stats = (float*)p;  p += (size_t)NB*NT*2*4;
    int*    cnt   = (int*)p;    p += (size_t)NB*NT*4;
    int*    flags = (int*)p;

    hipMemsetAsync(stats, 0, (size_t)(NB*NT*2*4 + NB*NT*4 + NT*NB*NHPQ*4), stream);
    hipLaunchKernelGGL(convlstm_persist, dim3(NHPQ, NB), dim3(512), 0, stream,
                       x, Wk, Uk, bias, gamma, beta,
                       hbuf0, hbuf1, out, stats, cnt, flags);
}